// Round 1
// baseline (36.775 us; speedup 1.0000x reference)
//
#include <hip/hip_runtime.h>

// DiffAugment fused: flip -> brightness -> contrast -> translation -> cutout
// B=64, C=3, H=W=256, fp32. One thread per output pixel; block = one W-row.

#define Bc 64
#define Cc 3
#define Hc 256
#define Wc 256

__global__ __launch_bounds__(256) void diffaug_kernel(
    const float* __restrict__ x,
    const float* __restrict__ p_,
    const float* __restrict__ flip_u,
    const float* __restrict__ bright_n,
    const float* __restrict__ bright_u,
    const float* __restrict__ contrast_n,
    const float* __restrict__ contrast_u,
    const int*   __restrict__ trans_h,
    const int*   __restrict__ trans_w,
    const float* __restrict__ trans_u,
    const int*   __restrict__ cut_ox,
    const int*   __restrict__ cut_oy,
    const float* __restrict__ cut_u,
    float* __restrict__ out)
{
    const int row = blockIdx.x;        // [0, B*C*H)
    const int w   = threadIdx.x;       // [0, W)
    const int h   = row & (Hc - 1);
    const int bc  = row >> 8;          // b*C + c   (H == 256)
    const int b   = bc / Cc;

    // Per-batch params — block-uniform, scalar-cached.
    const float p    = p_[0];
    const bool  flip = flip_u[b] < 0.5f * p;
    const float badd = (bright_u[b]   < p) ? bright_n[b]   * 0.2f : 0.0f;
    const float cmul = (contrast_u[b] < p) ? exp2f(contrast_n[b] * 0.5f) : 1.0f;
    const bool  do_t   = trans_u[b] < p;
    const bool  do_cut = cut_u[b]   < p;

    // Translation source coordinates (faithful to the torch quirks):
    //   gh = clip(h + th + 1, 0, H+1) into H-padded-by-1 image (rows 0, H+1 are zero)
    //   gw = (w + tw) mod (W-1), Python modulo (non-negative)
    int  hs = h, ws = w;
    bool zero = false;
    if (do_t) {
        int ghp = h + trans_h[b] + 1;
        ghp = min(max(ghp, 0), Hc + 1);
        zero = (ghp == 0) | (ghp == Hc + 1);
        hs = ghp - 1;
        int gw = (w + trans_w[b]) % (Wc - 1);
        if (gw < 0) gw += (Wc - 1);
        ws = gw;
    }

    float v = 0.0f;
    if (!zero) {
        const int wsrc = flip ? (Wc - 1 - ws) : ws;
        v = (x[(bc * Hc + hs) * Wc + wsrc] + badd) * cmul;
    }

    // Cutout: clamped 128x128 scatter collapses to a rectangle test
    // (clamp absorbed since h,w already in [0, 255]).
    if (do_cut) {
        const int ox = cut_ox[b], oy = cut_oy[b];
        if (h >= ox - 64 && h <= ox + 63 && w >= oy - 64 && w <= oy + 63)
            v = 0.0f;
    }

    out[(bc * Hc + h) * Wc + w] = v;
}

extern "C" void kernel_launch(void* const* d_in, const int* in_sizes, int n_in,
                              void* d_out, int out_size, void* d_ws, size_t ws_size,
                              hipStream_t stream) {
    const float* x          = (const float*)d_in[0];
    const float* p          = (const float*)d_in[1];
    const float* flip_u     = (const float*)d_in[2];
    const float* bright_n   = (const float*)d_in[3];
    const float* bright_u   = (const float*)d_in[4];
    const float* contrast_n = (const float*)d_in[5];
    const float* contrast_u = (const float*)d_in[6];
    const int*   trans_h    = (const int*)d_in[7];
    const int*   trans_w    = (const int*)d_in[8];
    const float* trans_u    = (const float*)d_in[9];
    const int*   cut_ox     = (const int*)d_in[10];
    const int*   cut_oy     = (const int*)d_in[11];
    const float* cut_u      = (const float*)d_in[12];
    float*       out        = (float*)d_out;

    dim3 grid(Bc * Cc * Hc);   // 49152 row-blocks
    dim3 block(Wc);            // 256 lanes = one W row
    diffaug_kernel<<<grid, block, 0, stream>>>(
        x, p, flip_u, bright_n, bright_u, contrast_n, contrast_u,
        trans_h, trans_w, trans_u, cut_ox, cut_oy, cut_u, out);
}

// Round 2
// 23.822 us; speedup vs baseline: 1.5438x; 1.5438x over previous
//
#include <hip/hip_runtime.h>

// DiffAugment fused: flip -> brightness -> contrast -> translation -> cutout
// B=64, C=3, H=W=256, fp32.
// One wave per output row; lane handles 4 pixels (float4 in/out).
// Source row staged via coalesced float4 loads into LDS, gathered from LDS
// (handles translation wrap + flip reversal without breaking coalescing).

#define Bc 64
#define Cc 3
#define Hc 256
#define Wc 256

__global__ __launch_bounds__(256) void diffaug_kernel(
    const float* __restrict__ x,
    const float* __restrict__ p_,
    const float* __restrict__ flip_u,
    const float* __restrict__ bright_n,
    const float* __restrict__ bright_u,
    const float* __restrict__ contrast_n,
    const float* __restrict__ contrast_u,
    const int*   __restrict__ trans_h,
    const int*   __restrict__ trans_w,
    const float* __restrict__ trans_u,
    const int*   __restrict__ cut_ox,
    const int*   __restrict__ cut_oy,
    const float* __restrict__ cut_u,
    float* __restrict__ out)
{
    __shared__ float srow[4][Wc];          // one 1 KB row per wave

    const int wave = threadIdx.x >> 6;
    const int lane = threadIdx.x & 63;
    const int row  = blockIdx.x * 4 + wave;   // [0, B*C*H)
    const int h    = row & (Hc - 1);
    const int bc   = row >> 8;                // b*C + c  (H == 256)
    const int b    = bc / Cc;

    // Per-batch params (wave-uniform).
    const float p    = p_[0];
    const bool  flip = flip_u[b] < 0.5f * p;
    const float badd = (bright_u[b]   < p) ? bright_n[b]   * 0.2f : 0.0f;
    const float cmul = (contrast_u[b] < p) ? exp2f(contrast_n[b] * 0.5f) : 1.0f;
    const bool  do_t   = trans_u[b] < p;
    const bool  do_cut = cut_u[b]   < p;

    // Translation source row (torch quirks: H padded by 1 each side, rows
    // 0 and H+1 of the padded image are zeros; w wraps mod (W-1)).
    int  hs = h, tw = 0;
    bool zero = false;
    if (do_t) {
        int ghp = h + trans_h[b] + 1;
        ghp  = min(max(ghp, 0), Hc + 1);
        zero = (ghp == 0) | (ghp == Hc + 1);
        hs   = min(max(ghp - 1, 0), Hc - 1);
        tw   = trans_w[b];
    }

    // Stage source row -> LDS, fully coalesced (64 lanes x float4 = 1 KB).
    if (!zero) {
        const float4 v4 = *reinterpret_cast<const float4*>(
            &x[(size_t)(bc * Hc + hs) * Wc + 4 * lane]);
        *reinterpret_cast<float4*>(&srow[wave][4 * lane]) = v4;
    }
    __syncthreads();

    float4 o;
    if (zero) {
        o = make_float4(0.f, 0.f, 0.f, 0.f);
    } else {
        #pragma unroll
        for (int j = 0; j < 4; ++j) {
            const int w = 4 * lane + j;
            int ws = w;
            if (do_t) {                       // python mod (W-1); w+tw in [-16,271]
                ws = w + tw;
                if (ws < 0)          ws += (Wc - 1);
                else if (ws >= Wc-1) ws -= (Wc - 1);
            }
            const int wsrc = flip ? (Wc - 1 - ws) : ws;
            (&o.x)[j] = (srow[wave][wsrc] + badd) * cmul;
        }
    }

    // Cutout: clamped 128x128 scatter == rectangle test (clamp absorbed).
    if (do_cut) {
        const int ox = cut_ox[b], oy = cut_oy[b];
        if (h >= ox - 64 && h <= ox + 63) {
            #pragma unroll
            for (int j = 0; j < 4; ++j) {
                const int w = 4 * lane + j;
                if (w >= oy - 64 && w <= oy + 63) (&o.x)[j] = 0.f;
            }
        }
    }

    *reinterpret_cast<float4*>(&out[(size_t)(bc * Hc + h) * Wc + 4 * lane]) = o;
}

extern "C" void kernel_launch(void* const* d_in, const int* in_sizes, int n_in,
                              void* d_out, int out_size, void* d_ws, size_t ws_size,
                              hipStream_t stream) {
    const float* x          = (const float*)d_in[0];
    const float* p          = (const float*)d_in[1];
    const float* flip_u     = (const float*)d_in[2];
    const float* bright_n   = (const float*)d_in[3];
    const float* bright_u   = (const float*)d_in[4];
    const float* contrast_n = (const float*)d_in[5];
    const float* contrast_u = (const float*)d_in[6];
    const int*   trans_h    = (const int*)d_in[7];
    const int*   trans_w    = (const int*)d_in[8];
    const float* trans_u    = (const float*)d_in[9];
    const int*   cut_ox     = (const int*)d_in[10];
    const int*   cut_oy     = (const int*)d_in[11];
    const float* cut_u      = (const float*)d_in[12];
    float*       out        = (float*)d_out;

    dim3 grid(Bc * Cc * Hc / 4);   // 12288 blocks, one row per wave
    dim3 block(256);
    diffaug_kernel<<<grid, block, 0, stream>>>(
        x, p, flip_u, bright_n, bright_u, contrast_n, contrast_u,
        trans_h, trans_w, trans_u, cut_ox, cut_oy, cut_u, out);
}

// Round 3
// 21.352 us; speedup vs baseline: 1.7224x; 1.1157x over previous
//
#include <hip/hip_runtime.h>

// DiffAugment fused: flip -> brightness -> contrast -> translation -> cutout
// B=64, C=3, H=W=256, fp32.
// One wave per TWO output rows (2 float4 loads/stores in flight); no block
// barrier (each wave owns its LDS rows); skewed LDS layout kills the 8-way
// stride-4 bank conflicts; register-direct fast path when no gather needed.

#define Bc 64
#define Cc 3
#define Hc 256
#define Wc 256

// Skewed LDS index: consecutive 32-float groups shifted by 1 slot.
// Read/write stride-4-float patterns (lanes l, l+8) become conflict-free.
#define SK(w) ((w) + ((w) >> 5))

__global__ __launch_bounds__(256) void diffaug_kernel(
    const float* __restrict__ x,
    const float* __restrict__ p_,
    const float* __restrict__ flip_u,
    const float* __restrict__ bright_n,
    const float* __restrict__ bright_u,
    const float* __restrict__ contrast_n,
    const float* __restrict__ contrast_u,
    const int*   __restrict__ trans_h,
    const int*   __restrict__ trans_w,
    const float* __restrict__ trans_u,
    const int*   __restrict__ cut_ox,
    const int*   __restrict__ cut_oy,
    const float* __restrict__ cut_u,
    float* __restrict__ out)
{
    __shared__ float srow[4][2][264];       // [wave][row-pair][skewed W]

    const int wave = threadIdx.x >> 6;
    const int lane = threadIdx.x & 63;
    const int r0   = blockIdx.x * 8 + wave * 2;   // even; r0,r0+1 share bc
    const int h0   = r0 & (Hc - 1);               // <= 254
    const int bc   = r0 >> 8;                     // b*C + c  (H == 256)
    const int b    = bc / Cc;

    // Per-batch params (wave-uniform, scalar-cached).
    const float p    = p_[0];
    const bool  flip = flip_u[b] < 0.5f * p;
    const float badd = (bright_u[b]   < p) ? bright_n[b]   * 0.2f : 0.0f;
    const float cmul = (contrast_u[b] < p) ? exp2f(contrast_n[b] * 0.5f) : 1.0f;
    const bool  do_t   = trans_u[b] < p;
    const bool  do_cut = cut_u[b]   < p;
    const int   ox = cut_ox[b], oy = cut_oy[b];

    const size_t obase = (size_t)(bc * Hc + h0) * Wc + 4 * lane;

    // ---------- fast path: no gather needed (register-direct) ----------
    if (!do_t && !flip) {
        float4 v0 = *reinterpret_cast<const float4*>(&x[obase]);
        float4 v1 = *reinterpret_cast<const float4*>(&x[obase + Wc]);
        #pragma unroll
        for (int i = 0; i < 2; ++i) {
            float4& v = i ? v1 : v0;
            const int h = h0 + i;
            #pragma unroll
            for (int j = 0; j < 4; ++j) {
                float o = ((&v.x)[j] + badd) * cmul;
                if (do_cut && h >= ox - 64 && h <= ox + 63) {
                    const int w = 4 * lane + j;
                    if (w >= oy - 64 && w <= oy + 63) o = 0.f;
                }
                (&v.x)[j] = o;
            }
            *reinterpret_cast<float4*>(&out[obase + i * Wc]) = v;
        }
        return;
    }

    // ---------- gather path ----------
    // Translation source rows (torch quirks: H padded by 1 each side; padded
    // rows 0 and H+1 are zero; w wraps python-mod (W-1)).
    int  tw = 0, hs0 = h0, hs1 = h0 + 1;
    bool zero0 = false, zero1 = false;
    if (do_t) {
        const int th = trans_h[b];
        tw = trans_w[b];
        int g0 = min(max(h0     + th + 1, 0), Hc + 1);
        int g1 = min(max(h0 + 1 + th + 1, 0), Hc + 1);
        zero0 = (g0 == 0) | (g0 == Hc + 1);
        zero1 = (g1 == 0) | (g1 == Hc + 1);
        hs0 = min(max(g0 - 1, 0), Hc - 1);
        hs1 = min(max(g1 - 1, 0), Hc - 1);
    }

    // Stage both source rows (coalesced float4 loads, both in flight).
    float4 v0 = make_float4(0.f, 0.f, 0.f, 0.f), v1 = v0;
    if (!zero0) v0 = *reinterpret_cast<const float4*>(
                         &x[(size_t)(bc * Hc + hs0) * Wc + 4 * lane]);
    if (!zero1) v1 = *reinterpret_cast<const float4*>(
                         &x[(size_t)(bc * Hc + hs1) * Wc + 4 * lane]);

    #pragma unroll
    for (int j = 0; j < 4; ++j) {
        srow[wave][0][SK(4 * lane + j)] = (&v0.x)[j];
        srow[wave][1][SK(4 * lane + j)] = (&v1.x)[j];
    }
    // No __syncthreads: producer and consumer are the same wave; the
    // compiler inserts the lgkmcnt waits for the LDS dependency.

    #pragma unroll
    for (int i = 0; i < 2; ++i) {
        const int h = h0 + i;
        const bool zr = i ? zero1 : zero0;
        float4 o;
        if (zr) {
            o = make_float4(0.f, 0.f, 0.f, 0.f);
        } else {
            #pragma unroll
            for (int j = 0; j < 4; ++j) {
                int ws = 4 * lane + j;
                if (do_t) {                 // python mod (W-1); in [-16, 271]
                    ws += tw;
                    if (ws < 0)            ws += (Wc - 1);
                    else if (ws >= Wc - 1) ws -= (Wc - 1);
                }
                const int wsrc = flip ? (Wc - 1 - ws) : ws;
                (&o.x)[j] = (srow[wave][i][SK(wsrc)] + badd) * cmul;
            }
        }
        if (do_cut && h >= ox - 64 && h <= ox + 63) {
            #pragma unroll
            for (int j = 0; j < 4; ++j) {
                const int w = 4 * lane + j;
                if (w >= oy - 64 && w <= oy + 63) (&o.x)[j] = 0.f;
            }
        }
        *reinterpret_cast<float4*>(&out[obase + i * Wc]) = o;
    }
}

extern "C" void kernel_launch(void* const* d_in, const int* in_sizes, int n_in,
                              void* d_out, int out_size, void* d_ws, size_t ws_size,
                              hipStream_t stream) {
    const float* x          = (const float*)d_in[0];
    const float* p          = (const float*)d_in[1];
    const float* flip_u     = (const float*)d_in[2];
    const float* bright_n   = (const float*)d_in[3];
    const float* bright_u   = (const float*)d_in[4];
    const float* contrast_n = (const float*)d_in[5];
    const float* contrast_u = (const float*)d_in[6];
    const int*   trans_h    = (const int*)d_in[7];
    const int*   trans_w    = (const int*)d_in[8];
    const float* trans_u    = (const float*)d_in[9];
    const int*   cut_ox     = (const int*)d_in[10];
    const int*   cut_oy     = (const int*)d_in[11];
    const float* cut_u      = (const float*)d_in[12];
    float*       out        = (float*)d_out;

    dim3 grid(Bc * Cc * Hc / 8);   // 6144 blocks, 2 rows per wave
    dim3 block(256);
    diffaug_kernel<<<grid, block, 0, stream>>>(
        x, p, flip_u, bright_n, bright_u, contrast_n, contrast_u,
        trans_h, trans_w, trans_u, cut_ox, cut_oy, cut_u, out);
}

// Round 4
// 20.723 us; speedup vs baseline: 1.7746x; 1.0303x over previous
//
#include <hip/hip_runtime.h>

// DiffAugment fused: flip -> brightness -> contrast -> translation -> cutout
// B=64, C=3, H=W=256, fp32.
// One wave per (b,h) row, handling ALL 3 channels (index math amortized).
// b is blockIdx-derived -> params scalarize to s_loads.
// Paths: (1) direct, (2) flip-only: reversed aligned float4 load,
//        (3) translated: LDS gather with skewed layout (conflict-free).
// Brightness+contrast+cutout fold to one FMA per pixel: o = v*scl + off.

#define Bc 64
#define Cc 3
#define Hc 256
#define Wc 256
#define CH (Hc * Wc)

// Skew: consecutive 32-float groups shifted by 1 slot -> stride-4 scalar
// access patterns become (free) 2-way instead of 8-way bank conflicts.
#define SK(w) ((w) + ((w) >> 5))

__global__ __launch_bounds__(256) void diffaug_kernel(
    const float* __restrict__ x,
    const float* __restrict__ p_,
    const float* __restrict__ flip_u,
    const float* __restrict__ bright_n,
    const float* __restrict__ bright_u,
    const float* __restrict__ contrast_n,
    const float* __restrict__ contrast_u,
    const int*   __restrict__ trans_h,
    const int*   __restrict__ trans_w,
    const float* __restrict__ trans_u,
    const int*   __restrict__ cut_ox,
    const int*   __restrict__ cut_oy,
    const float* __restrict__ cut_u,
    float* __restrict__ out)
{
    __shared__ float srow[4][Cc][264];   // [wave][channel][skewed W] ~12.4 KB

    const int wave = threadIdx.x >> 6;
    const int lane = threadIdx.x & 63;
    const int b    = blockIdx.x >> 6;                  // block-uniform (SGPR)
    const int h    = ((blockIdx.x & 63) << 2) | wave;  // wave-uniform
    const int w0   = lane << 2;

    // Per-image params — uniform address -> scalar loads.
    const float p    = p_[0];
    const bool  flip = flip_u[b] < 0.5f * p;
    const float badd = (bright_u[b]   < p) ? bright_n[b]   * 0.2f : 0.0f;
    const float cmul = (contrast_u[b] < p) ? exp2f(contrast_n[b] * 0.5f) : 1.0f;
    const bool  do_t   = trans_u[b] < p;
    const bool  do_cut = cut_u[b]   < p;
    const int   ox = cut_ox[b], oy = cut_oy[b];

    // Fold brightness/contrast/cutout into one fma per pixel: o = v*scl+off.
    // Cutout clamp is absorbed (h,w already in [0,255]).
    const bool hcut = do_cut && (h >= ox - 64) && (h <= ox + 63);
    float scl[4], off[4];
    #pragma unroll
    for (int j = 0; j < 4; ++j) {
        const int w = w0 + j;
        const bool cut = hcut && (w >= oy - 64) && (w <= oy + 63);
        scl[j] = cut ? 0.f : cmul;
        off[j] = cut ? 0.f : badd * cmul;
    }

    const size_t rowbase = (size_t)(b * Cc) * CH + (size_t)h * Wc + w0;

    if (!do_t) {
        if (!flip) {
            // ---- path 1: pure elementwise ----
            #pragma unroll
            for (int c = 0; c < Cc; ++c) {
                float4 v = *reinterpret_cast<const float4*>(&x[rowbase + c * CH]);
                float4 o;
                o.x = v.x * scl[0] + off[0];
                o.y = v.y * scl[1] + off[1];
                o.z = v.z * scl[2] + off[2];
                o.w = v.w * scl[3] + off[3];
                *reinterpret_cast<float4*>(&out[rowbase + c * CH]) = o;
            }
        } else {
            // ---- path 2: flip-only. out[4l+j] = row[255-(4l+j)]; load the
            // aligned window [252-4l .. 255-4l], reverse in registers.
            const size_t rb = (size_t)(b * Cc) * CH + (size_t)h * Wc + (252 - w0);
            #pragma unroll
            for (int c = 0; c < Cc; ++c) {
                float4 v = *reinterpret_cast<const float4*>(&x[rb + c * CH]);
                float4 o;
                o.x = v.w * scl[0] + off[0];
                o.y = v.z * scl[1] + off[1];
                o.z = v.y * scl[2] + off[2];
                o.w = v.x * scl[3] + off[3];
                *reinterpret_cast<float4*>(&out[rowbase + c * CH]) = o;
            }
        }
        return;
    }

    // ---- path 3: translation (flip folded into gather index) ----
    // torch quirks: H padded by 1 each side (pad rows are zero), w wraps
    // python-mod (W-1).
    const int th = trans_h[b], tw = trans_w[b];
    int g = h + th + 1;
    g = min(max(g, 0), Hc + 1);
    const bool zero = (g == 0) | (g == Hc + 1);

    if (zero) {
        const float4 z = make_float4(0.f, 0.f, 0.f, 0.f);
        #pragma unroll
        for (int c = 0; c < Cc; ++c)
            *reinterpret_cast<float4*>(&out[rowbase + c * CH]) = z;
        return;
    }

    const int hs = min(max(g - 1, 0), Hc - 1);
    const size_t sbase = (size_t)(b * Cc) * CH + (size_t)hs * Wc + w0;

    // Stage 3 source rows (3 coalesced float4 loads in flight).
    float4 v0 = *reinterpret_cast<const float4*>(&x[sbase]);
    float4 v1 = *reinterpret_cast<const float4*>(&x[sbase + CH]);
    float4 v2 = *reinterpret_cast<const float4*>(&x[sbase + 2 * CH]);
    #pragma unroll
    for (int j = 0; j < 4; ++j) {
        srow[wave][0][SK(w0 + j)] = (&v0.x)[j];
        srow[wave][1][SK(w0 + j)] = (&v1.x)[j];
        srow[wave][2][SK(w0 + j)] = (&v2.x)[j];
    }
    // No __syncthreads: producer wave == consumer wave.

    // Gather indices once, reused for all 3 channels.
    int sk[4];
    #pragma unroll
    for (int j = 0; j < 4; ++j) {
        int ws = w0 + j + tw;                 // in [-16, 271]
        if (ws < 0)            ws += (Wc - 1);
        else if (ws >= Wc - 1) ws -= (Wc - 1);
        const int wsrc = flip ? (Wc - 1 - ws) : ws;
        sk[j] = SK(wsrc);
    }

    #pragma unroll
    for (int c = 0; c < Cc; ++c) {
        float4 o;
        #pragma unroll
        for (int j = 0; j < 4; ++j)
            (&o.x)[j] = srow[wave][c][sk[j]] * scl[j] + off[j];
        *reinterpret_cast<float4*>(&out[rowbase + c * CH]) = o;
    }
}

extern "C" void kernel_launch(void* const* d_in, const int* in_sizes, int n_in,
                              void* d_out, int out_size, void* d_ws, size_t ws_size,
                              hipStream_t stream) {
    const float* x          = (const float*)d_in[0];
    const float* p          = (const float*)d_in[1];
    const float* flip_u     = (const float*)d_in[2];
    const float* bright_n   = (const float*)d_in[3];
    const float* bright_u   = (const float*)d_in[4];
    const float* contrast_n = (const float*)d_in[5];
    const float* contrast_u = (const float*)d_in[6];
    const int*   trans_h    = (const int*)d_in[7];
    const int*   trans_w    = (const int*)d_in[8];
    const float* trans_u    = (const float*)d_in[9];
    const int*   cut_ox     = (const int*)d_in[10];
    const int*   cut_oy     = (const int*)d_in[11];
    const float* cut_u      = (const float*)d_in[12];
    float*       out        = (float*)d_out;

    dim3 grid(Bc * Hc / 4);    // 4096 blocks: (b, h-quad); wave = one (b,h) row
    dim3 block(256);
    diffaug_kernel<<<grid, block, 0, stream>>>(
        x, p, flip_u, bright_n, bright_u, contrast_n, contrast_u,
        trans_h, trans_w, trans_u, cut_ox, cut_oy, cut_u, out);
}

// Round 5
// 20.291 us; speedup vs baseline: 1.8124x; 1.0213x over previous
//
#include <hip/hip_runtime.h>

// DiffAugment fused: flip -> brightness -> contrast -> translation -> cutout
// B=64, C=3, H=W=256, fp32.
// One wave per (b,h) row, all 3 channels. b is blockIdx-derived -> params
// scalarize. Paths: direct / flip (reversed aligned load) / translated
// (LDS gather, skewed). Output written with NONTEMPORAL stores so the write
// stream doesn't allocate in L2/L3 -> the 50 MB input stays L3-resident
// across graph replays and reads stop hitting HBM.

#define Bc 64
#define Cc 3
#define Hc 256
#define Wc 256
#define CH (Hc * Wc)

typedef float f32x4 __attribute__((ext_vector_type(4)));

// Skew: consecutive 32-float groups shifted by 1 slot -> stride-4 scalar
// access becomes (free) 2-way instead of 8-way bank conflict.
#define SK(w) ((w) + ((w) >> 5))

__device__ __forceinline__ void store_nt(float* p, f32x4 v) {
    __builtin_nontemporal_store(v, reinterpret_cast<f32x4*>(p));
}

__global__ __launch_bounds__(256) void diffaug_kernel(
    const float* __restrict__ x,
    const float* __restrict__ p_,
    const float* __restrict__ flip_u,
    const float* __restrict__ bright_n,
    const float* __restrict__ bright_u,
    const float* __restrict__ contrast_n,
    const float* __restrict__ contrast_u,
    const int*   __restrict__ trans_h,
    const int*   __restrict__ trans_w,
    const float* __restrict__ trans_u,
    const int*   __restrict__ cut_ox,
    const int*   __restrict__ cut_oy,
    const float* __restrict__ cut_u,
    float* __restrict__ out)
{
    __shared__ float srow[4][Cc][264];   // [wave][channel][skewed W] ~12.4 KB

    const int wave = threadIdx.x >> 6;
    const int lane = threadIdx.x & 63;
    const int b    = blockIdx.x >> 6;                  // block-uniform (SGPR)
    const int h    = ((blockIdx.x & 63) << 2) | wave;  // wave-uniform
    const int w0   = lane << 2;

    // Per-image params — uniform address -> scalar loads.
    const float p    = p_[0];
    const bool  flip = flip_u[b] < 0.5f * p;
    const float badd = (bright_u[b]   < p) ? bright_n[b]   * 0.2f : 0.0f;
    const float cmul = (contrast_u[b] < p) ? exp2f(contrast_n[b] * 0.5f) : 1.0f;
    const bool  do_t   = trans_u[b] < p;
    const bool  do_cut = cut_u[b]   < p;
    const int   ox = cut_ox[b], oy = cut_oy[b];

    // Fold brightness/contrast/cutout into one fma per pixel: o = v*scl+off.
    const bool hcut = do_cut && (h >= ox - 64) && (h <= ox + 63);
    float scl[4], off[4];
    #pragma unroll
    for (int j = 0; j < 4; ++j) {
        const int w = w0 + j;
        const bool cut = hcut && (w >= oy - 64) && (w <= oy + 63);
        scl[j] = cut ? 0.f : cmul;
        off[j] = cut ? 0.f : badd * cmul;
    }

    const size_t rowbase = (size_t)(b * Cc) * CH + (size_t)h * Wc + w0;

    if (!do_t) {
        if (!flip) {
            // ---- path 1: pure elementwise ----
            #pragma unroll
            for (int c = 0; c < Cc; ++c) {
                f32x4 v = *reinterpret_cast<const f32x4*>(&x[rowbase + c * CH]);
                f32x4 o;
                o[0] = v[0] * scl[0] + off[0];
                o[1] = v[1] * scl[1] + off[1];
                o[2] = v[2] * scl[2] + off[2];
                o[3] = v[3] * scl[3] + off[3];
                store_nt(&out[rowbase + c * CH], o);
            }
        } else {
            // ---- path 2: flip-only: reversed aligned float4 window ----
            const size_t rb = (size_t)(b * Cc) * CH + (size_t)h * Wc + (252 - w0);
            #pragma unroll
            for (int c = 0; c < Cc; ++c) {
                f32x4 v = *reinterpret_cast<const f32x4*>(&x[rb + c * CH]);
                f32x4 o;
                o[0] = v[3] * scl[0] + off[0];
                o[1] = v[2] * scl[1] + off[1];
                o[2] = v[1] * scl[2] + off[2];
                o[3] = v[0] * scl[3] + off[3];
                store_nt(&out[rowbase + c * CH], o);
            }
        }
        return;
    }

    // ---- path 3: translation (flip folded into gather index) ----
    // torch quirks: H padded by 1 each side (pad rows zero); w wraps
    // python-mod (W-1).
    const int th = trans_h[b], tw = trans_w[b];
    int g = h + th + 1;
    g = min(max(g, 0), Hc + 1);
    const bool zero = (g == 0) | (g == Hc + 1);

    if (zero) {
        const f32x4 z = {0.f, 0.f, 0.f, 0.f};
        #pragma unroll
        for (int c = 0; c < Cc; ++c)
            store_nt(&out[rowbase + c * CH], z);
        return;
    }

    const int hs = min(max(g - 1, 0), Hc - 1);
    const size_t sbase = (size_t)(b * Cc) * CH + (size_t)hs * Wc + w0;

    // Stage 3 source rows (3 coalesced float4 loads in flight).
    f32x4 v0 = *reinterpret_cast<const f32x4*>(&x[sbase]);
    f32x4 v1 = *reinterpret_cast<const f32x4*>(&x[sbase + CH]);
    f32x4 v2 = *reinterpret_cast<const f32x4*>(&x[sbase + 2 * CH]);
    #pragma unroll
    for (int j = 0; j < 4; ++j) {
        srow[wave][0][SK(w0 + j)] = v0[j];
        srow[wave][1][SK(w0 + j)] = v1[j];
        srow[wave][2][SK(w0 + j)] = v2[j];
    }
    // No __syncthreads: producer wave == consumer wave.

    // Gather indices once, reused for all 3 channels.
    int sk[4];
    #pragma unroll
    for (int j = 0; j < 4; ++j) {
        int ws = w0 + j + tw;                 // in [-16, 271]
        if (ws < 0)            ws += (Wc - 1);
        else if (ws >= Wc - 1) ws -= (Wc - 1);
        const int wsrc = flip ? (Wc - 1 - ws) : ws;
        sk[j] = SK(wsrc);
    }

    #pragma unroll
    for (int c = 0; c < Cc; ++c) {
        f32x4 o;
        #pragma unroll
        for (int j = 0; j < 4; ++j)
            o[j] = srow[wave][c][sk[j]] * scl[j] + off[j];
        store_nt(&out[rowbase + c * CH], o);
    }
}

extern "C" void kernel_launch(void* const* d_in, const int* in_sizes, int n_in,
                              void* d_out, int out_size, void* d_ws, size_t ws_size,
                              hipStream_t stream) {
    const float* x          = (const float*)d_in[0];
    const float* p          = (const float*)d_in[1];
    const float* flip_u     = (const float*)d_in[2];
    const float* bright_n   = (const float*)d_in[3];
    const float* bright_u   = (const float*)d_in[4];
    const float* contrast_n = (const float*)d_in[5];
    const float* contrast_u = (const float*)d_in[6];
    const int*   trans_h    = (const int*)d_in[7];
    const int*   trans_w    = (const int*)d_in[8];
    const float* trans_u    = (const float*)d_in[9];
    const int*   cut_ox     = (const int*)d_in[10];
    const int*   cut_oy     = (const int*)d_in[11];
    const float* cut_u      = (const float*)d_in[12];
    float*       out        = (float*)d_out;

    dim3 grid(Bc * Hc / 4);    // 4096 blocks: (b, h-quad); wave = one (b,h) row
    dim3 block(256);
    diffaug_kernel<<<grid, block, 0, stream>>>(
        x, p, flip_u, bright_n, bright_u, contrast_n, contrast_u,
        trans_h, trans_w, trans_u, cut_ox, cut_oy, cut_u, out);
}